// Round 3
// baseline (316.671 us; speedup 1.0000x reference)
//
#include <hip/hip_runtime.h>

// TinyDLRM v2b: out[i] = sigmoid( relu( f @ w1 + b1 ) @ w2 + b2 )
// f = [user_emb(8) | item_emb(8) | cat_emb(8) | dense(2)]  (26 fp32)
//
// v1 post-mortem: 163 us, VALUBusy 32%, HBM 43% -> latency-bound on gathers
// (one dependent id->gather chain per thread, only 6 outstanding gathers/wave).
// v2: 4 samples per thread.
//  - ids/dense/out become vector stream accesses (nontemporal, so the ~100 MB
//    of streaming traffic doesn't evict the 64 MB tables from L2/L3)
//  - 24 gather float4s issued back-to-back per thread -> 4x memory-level
//    parallelism per wave, trading occupancy (VGPRs) we don't need (VALU 32%).
// v2b: __builtin_nontemporal_* requires native clang vectors, not
//      HIP_vector_type structs -> use ext_vector_type aliases.

#define HIDDEN 16
#define IN_DIM 26
#define SPT 4  // samples per thread

typedef int   iv4 __attribute__((ext_vector_type(4)));
typedef float fv4 __attribute__((ext_vector_type(4)));

__global__ __launch_bounds__(256) void tiny_dlrm_kernel(
    const int*   __restrict__ user_id,
    const int*   __restrict__ item_id,
    const int*   __restrict__ cat_id,
    const float* __restrict__ dense,      // [B,2]
    const float* __restrict__ user_table, // [NU,8]
    const float* __restrict__ item_table, // [NI,8]
    const float* __restrict__ cat_table,  // [NC,8]
    const float* __restrict__ w1,         // [26,16] row-major
    const float* __restrict__ b1,         // [16]
    const float* __restrict__ w2,         // [16]
    const float* __restrict__ b2,         // [1]
    float*       __restrict__ out,        // [B]
    int batch)
{
    int t = blockIdx.x * blockDim.x + threadIdx.x;
    long long base = (long long)t * SPT;
    if (base + SPT - 1 >= batch) {
        // generic tail (not hit when batch % (256*SPT) == 0)
        for (long long s = base; s < batch; ++s) {
            int u = user_id[s], v = item_id[s], c = cat_id[s];
            const float* up = user_table + (size_t)u * 8;
            const float* ip = item_table + (size_t)v * 8;
            const float* cp = cat_table  + (size_t)c * 8;
            float f[IN_DIM];
            for (int k = 0; k < 8; ++k) { f[k] = up[k]; f[8+k] = ip[k]; f[16+k] = cp[k]; }
            f[24] = dense[s*2]; f[25] = dense[s*2+1];
            float acc = b2[0];
            for (int j = 0; j < HIDDEN; ++j) {
                float h = b1[j];
                for (int k = 0; k < IN_DIM; ++k) h = fmaf(f[k], w1[k*HIDDEN+j], h);
                acc = fmaf(fmaxf(h, 0.0f), w2[j], acc);
            }
            out[s] = 1.0f / (1.0f + __expf(-acc));
        }
        return;
    }

    // --- stream loads (nontemporal: keep L2/L3 for the tables) ---
    iv4 u4 = __builtin_nontemporal_load((const iv4*)user_id + t);
    iv4 v4 = __builtin_nontemporal_load((const iv4*)item_id + t);
    iv4 c4 = __builtin_nontemporal_load((const iv4*)cat_id  + t);
    fv4 d0 = __builtin_nontemporal_load((const fv4*)dense + 2*t);
    fv4 d1 = __builtin_nontemporal_load((const fv4*)dense + 2*t + 1);

    int uu[SPT] = {u4.x, u4.y, u4.z, u4.w};
    int vv[SPT] = {v4.x, v4.y, v4.z, v4.w};
    int cc[SPT] = {c4.x, c4.y, c4.z, c4.w};

    // --- issue all 24 gather loads (max memory-level parallelism) ---
    float4 g[SPT][6];
#pragma unroll
    for (int s = 0; s < SPT; ++s) {
        const float4* up = (const float4*)(user_table + (size_t)uu[s] * 8);
        const float4* ip = (const float4*)(item_table + (size_t)vv[s] * 8);
        const float4* cp = (const float4*)(cat_table  + (size_t)cc[s] * 8);
        g[s][0] = up[0]; g[s][1] = up[1];
        g[s][2] = ip[0]; g[s][3] = ip[1];
        g[s][4] = cp[0]; g[s][5] = cp[1];
    }

    float dd[SPT][2] = {{d0.x, d0.y}, {d0.z, d0.w}, {d1.x, d1.y}, {d1.z, d1.w}};

    float o[SPT];
#pragma unroll
    for (int s = 0; s < SPT; ++s) {
        float f[IN_DIM] = {
            g[s][0].x, g[s][0].y, g[s][0].z, g[s][0].w,
            g[s][1].x, g[s][1].y, g[s][1].z, g[s][1].w,
            g[s][2].x, g[s][2].y, g[s][2].z, g[s][2].w,
            g[s][3].x, g[s][3].y, g[s][3].z, g[s][3].w,
            g[s][4].x, g[s][4].y, g[s][4].z, g[s][4].w,
            g[s][5].x, g[s][5].y, g[s][5].z, g[s][5].w,
            dd[s][0], dd[s][1]
        };

        float h[HIDDEN];
#pragma unroll
        for (int j = 0; j < HIDDEN; ++j) h[j] = b1[j];
#pragma unroll
        for (int k = 0; k < IN_DIM; ++k) {
            float fk = f[k];
#pragma unroll
            for (int j = 0; j < HIDDEN; ++j)
                h[j] = fmaf(fk, w1[k * HIDDEN + j], h[j]);
        }
        float acc = b2[0];
#pragma unroll
        for (int j = 0; j < HIDDEN; ++j)
            acc = fmaf(fmaxf(h[j], 0.0f), w2[j], acc);
        o[s] = 1.0f / (1.0f + __expf(-acc));
    }

    fv4 o4 = {o[0], o[1], o[2], o[3]};
    __builtin_nontemporal_store(o4, (fv4*)out + t);
}

extern "C" void kernel_launch(void* const* d_in, const int* in_sizes, int n_in,
                              void* d_out, int out_size, void* d_ws, size_t ws_size,
                              hipStream_t stream) {
    const int*   user_id    = (const int*)d_in[0];
    const int*   item_id    = (const int*)d_in[1];
    const int*   cat_id     = (const int*)d_in[2];
    const float* dense      = (const float*)d_in[3];
    const float* user_table = (const float*)d_in[4];
    const float* item_table = (const float*)d_in[5];
    const float* cat_table  = (const float*)d_in[6];
    const float* w1         = (const float*)d_in[7];
    const float* b1         = (const float*)d_in[8];
    const float* w2         = (const float*)d_in[9];
    const float* b2         = (const float*)d_in[10];
    float* out = (float*)d_out;

    int batch = in_sizes[0];
    int block = 256;
    long long threads = ((long long)batch + SPT - 1) / SPT;
    int grid = (int)((threads + block - 1) / block);
    tiny_dlrm_kernel<<<grid, block, 0, stream>>>(
        user_id, item_id, cat_id, dense,
        user_table, item_table, cat_table,
        w1, b1, w2, b2, out, batch);
}

// Round 4
// 303.377 us; speedup vs baseline: 1.0438x; 1.0438x over previous
//
#include <hip/hip_runtime.h>

// TinyDLRM v3: out[i] = sigmoid( relu( f @ w1 + b1 ) @ w2 + b2 )
// f = [user_emb(8) | item_emb(8) | cat_emb(8) | dense(2)]  (26 fp32)
//
// Evidence so far: v1 (SPT=1) 163us @ 570MB, v2 (SPT=4) 185us @ 647MB --
// both EXACTLY 3.50 TB/s of L2-fill traffic despite 2.3x different
// outstanding-request counts => random-64B-sector fabric bandwidth ceiling,
// time ~ bytes/3.5TB/s. Byte floor ~535 MB (84 MB streams + 2x4.19Mx64B
// user/item sectors, cat L2-resident). v2's +77MB = occupancy drop losing
// residual L2 reuse.
//
// v3: SPT=2 midpoint -- 12 in-flight gathers/thread (2x v1's MLW) while
// keeping v1-class occupancy (launch_bounds(256,6) caps VGPR at 85);
// nontemporal hints ONLY on touch-once streams (ids/dense/out) so they
// don't churn table lines out of L2.

#define HIDDEN 16
#define IN_DIM 26
#define SPT 2  // samples per thread

typedef int   iv2 __attribute__((ext_vector_type(2)));
typedef float fv2 __attribute__((ext_vector_type(2)));
typedef float fv4 __attribute__((ext_vector_type(4)));

__global__ __launch_bounds__(256, 6) void tiny_dlrm_kernel(
    const int*   __restrict__ user_id,
    const int*   __restrict__ item_id,
    const int*   __restrict__ cat_id,
    const float* __restrict__ dense,      // [B,2]
    const float* __restrict__ user_table, // [NU,8]
    const float* __restrict__ item_table, // [NI,8]
    const float* __restrict__ cat_table,  // [NC,8]
    const float* __restrict__ w1,         // [26,16] row-major
    const float* __restrict__ b1,         // [16]
    const float* __restrict__ w2,         // [16]
    const float* __restrict__ b2,         // [1]
    float*       __restrict__ out,        // [B]
    int batch)
{
    int t = blockIdx.x * blockDim.x + threadIdx.x;
    long long base = (long long)t * SPT;
    if (base + SPT - 1 >= batch) {
        for (long long s = base; s < batch; ++s) {
            int u = user_id[s], v = item_id[s], c = cat_id[s];
            const float* up = user_table + (size_t)u * 8;
            const float* ip = item_table + (size_t)v * 8;
            const float* cp = cat_table  + (size_t)c * 8;
            float f[IN_DIM];
            for (int k = 0; k < 8; ++k) { f[k] = up[k]; f[8+k] = ip[k]; f[16+k] = cp[k]; }
            f[24] = dense[s*2]; f[25] = dense[s*2+1];
            float acc = b2[0];
            for (int j = 0; j < HIDDEN; ++j) {
                float h = b1[j];
                for (int k = 0; k < IN_DIM; ++k) h = fmaf(f[k], w1[k*HIDDEN+j], h);
                acc = fmaf(fmaxf(h, 0.0f), w2[j], acc);
            }
            out[s] = 1.0f / (1.0f + __expf(-acc));
        }
        return;
    }

    // --- touch-once streams: nontemporal so they don't evict table lines ---
    iv2 u2 = __builtin_nontemporal_load((const iv2*)user_id + t);
    iv2 v2 = __builtin_nontemporal_load((const iv2*)item_id + t);
    iv2 c2 = __builtin_nontemporal_load((const iv2*)cat_id  + t);
    fv4 dd = __builtin_nontemporal_load((const fv4*)dense + t);

    int uu[SPT] = {u2.x, u2.y};
    int vv[SPT] = {v2.x, v2.y};
    int cc[SPT] = {c2.x, c2.y};

    // --- issue all 12 gather loads back-to-back (memory-level parallelism) ---
    float4 g[SPT][6];
#pragma unroll
    for (int s = 0; s < SPT; ++s) {
        const float4* up = (const float4*)(user_table + (size_t)uu[s] * 8);
        const float4* ip = (const float4*)(item_table + (size_t)vv[s] * 8);
        const float4* cp = (const float4*)(cat_table  + (size_t)cc[s] * 8);
        g[s][0] = up[0]; g[s][1] = up[1];
        g[s][2] = ip[0]; g[s][3] = ip[1];
        g[s][4] = cp[0]; g[s][5] = cp[1];
    }

    float dpair[SPT][2] = {{dd.x, dd.y}, {dd.z, dd.w}};

    float o[SPT];
#pragma unroll
    for (int s = 0; s < SPT; ++s) {
        float f[IN_DIM] = {
            g[s][0].x, g[s][0].y, g[s][0].z, g[s][0].w,
            g[s][1].x, g[s][1].y, g[s][1].z, g[s][1].w,
            g[s][2].x, g[s][2].y, g[s][2].z, g[s][2].w,
            g[s][3].x, g[s][3].y, g[s][3].z, g[s][3].w,
            g[s][4].x, g[s][4].y, g[s][4].z, g[s][4].w,
            g[s][5].x, g[s][5].y, g[s][5].z, g[s][5].w,
            dpair[s][0], dpair[s][1]
        };

        float h[HIDDEN];
#pragma unroll
        for (int j = 0; j < HIDDEN; ++j) h[j] = b1[j];
#pragma unroll
        for (int k = 0; k < IN_DIM; ++k) {
            float fk = f[k];
#pragma unroll
            for (int j = 0; j < HIDDEN; ++j)
                h[j] = fmaf(fk, w1[k * HIDDEN + j], h[j]);
        }
        float acc = b2[0];
#pragma unroll
        for (int j = 0; j < HIDDEN; ++j)
            acc = fmaf(fmaxf(h[j], 0.0f), w2[j], acc);
        o[s] = 1.0f / (1.0f + __expf(-acc));
    }

    fv2 o2 = {o[0], o[1]};
    __builtin_nontemporal_store(o2, (fv2*)out + t);
}

extern "C" void kernel_launch(void* const* d_in, const int* in_sizes, int n_in,
                              void* d_out, int out_size, void* d_ws, size_t ws_size,
                              hipStream_t stream) {
    const int*   user_id    = (const int*)d_in[0];
    const int*   item_id    = (const int*)d_in[1];
    const int*   cat_id     = (const int*)d_in[2];
    const float* dense      = (const float*)d_in[3];
    const float* user_table = (const float*)d_in[4];
    const float* item_table = (const float*)d_in[5];
    const float* cat_table  = (const float*)d_in[6];
    const float* w1         = (const float*)d_in[7];
    const float* b1         = (const float*)d_in[8];
    const float* w2         = (const float*)d_in[9];
    const float* b2         = (const float*)d_in[10];
    float* out = (float*)d_out;

    int batch = in_sizes[0];
    int block = 256;
    long long threads = ((long long)batch + SPT - 1) / SPT;
    int grid = (int)((threads + block - 1) / block);
    tiny_dlrm_kernel<<<grid, block, 0, stream>>>(
        user_id, item_id, cat_id, dense,
        user_table, item_table, cat_table,
        w1, b1, w2, b2, out, batch);
}

// Round 5
// 295.474 us; speedup vs baseline: 1.0717x; 1.0267x over previous
//
#include <hip/hip_runtime.h>

// TinyDLRM v4: out[i] = sigmoid( relu( f @ w1 + b1 ) @ w2 + b2 )
//
// Evidence (v1/v2/v3): time == FETCH_SIZE / 3.5 TB/s exactly across three
// structurally different kernels -> random-64B-sector fetch-bandwidth ceiling.
// Only lever left: fetch fewer bytes. v1 gathers = 8.4M line-requests
// (user+item), 456 MB fetched => 44% L1/L2 hit rate vs 64 MB fp32 footprint.
// v4: repack user+item tables to fp16 in d_ws every call (32 MB footprint,
// 16 B rows -> 4 rows per 64 B line) to raise the gather hit rate.
// Repack = 72 MB streaming (~10 us). Cat table stays fp32 (L2-resident).
// Fallback to the proven fp32 path if ws_size is too small.

#define HIDDEN 16
#define IN_DIM 26

typedef _Float16 hv8 __attribute__((ext_vector_type(8)));

// ---------------- repack: fp32 [rows,8] -> fp16 [rows,8] ----------------
__global__ __launch_bounds__(256) void repack_kernel(
    const float* __restrict__ user_table,
    const float* __restrict__ item_table,
    _Float16*    __restrict__ user_h,
    _Float16*    __restrict__ item_h,
    int rows_per_table)
{
    int i = blockIdx.x * blockDim.x + threadIdx.x;
    const float* src;
    _Float16* dst;
    int r;
    if (i < rows_per_table) {
        src = user_table; dst = user_h; r = i;
    } else if (i < 2 * rows_per_table) {
        src = item_table; dst = item_h; r = i - rows_per_table;
    } else {
        return;
    }
    float4 a = ((const float4*)src)[2 * r];
    float4 b = ((const float4*)src)[2 * r + 1];
    hv8 h = {(_Float16)a.x, (_Float16)a.y, (_Float16)a.z, (_Float16)a.w,
             (_Float16)b.x, (_Float16)b.y, (_Float16)b.z, (_Float16)b.w};
    ((hv8*)dst)[r] = h;
}

// ---------------- main kernel, fp16 user/item tables ----------------
__global__ __launch_bounds__(256) void tiny_dlrm_h_kernel(
    const int*      __restrict__ user_id,
    const int*      __restrict__ item_id,
    const int*      __restrict__ cat_id,
    const float*    __restrict__ dense,      // [B,2]
    const _Float16* __restrict__ user_h,     // [NU,8] fp16
    const _Float16* __restrict__ item_h,     // [NI,8] fp16
    const float*    __restrict__ cat_table,  // [NC,8] fp32
    const float*    __restrict__ w1,         // [26,16]
    const float*    __restrict__ b1,
    const float*    __restrict__ w2,
    const float*    __restrict__ b2,
    float*          __restrict__ out,
    int batch)
{
    int i = blockIdx.x * blockDim.x + threadIdx.x;
    if (i >= batch) return;

    int u = user_id[i];
    int v = item_id[i];
    int c = cat_id[i];

    hv8 ur = ((const hv8*)user_h)[u];                       // 16 B, one line
    hv8 ir = ((const hv8*)item_h)[v];                       // 16 B, one line
    const float4* cp = (const float4*)(cat_table + (size_t)c * 8);
    float4 c0 = cp[0], c1 = cp[1];                          // L2-resident
    float2 dd = ((const float2*)dense)[i];

    float f[IN_DIM] = {
        (float)ur[0], (float)ur[1], (float)ur[2], (float)ur[3],
        (float)ur[4], (float)ur[5], (float)ur[6], (float)ur[7],
        (float)ir[0], (float)ir[1], (float)ir[2], (float)ir[3],
        (float)ir[4], (float)ir[5], (float)ir[6], (float)ir[7],
        c0.x, c0.y, c0.z, c0.w, c1.x, c1.y, c1.z, c1.w,
        dd.x, dd.y
    };

    float h[HIDDEN];
#pragma unroll
    for (int j = 0; j < HIDDEN; ++j) h[j] = b1[j];
#pragma unroll
    for (int k = 0; k < IN_DIM; ++k) {
        float fk = f[k];
#pragma unroll
        for (int j = 0; j < HIDDEN; ++j)
            h[j] = fmaf(fk, w1[k * HIDDEN + j], h[j]);
    }
    float acc = b2[0];
#pragma unroll
    for (int j = 0; j < HIDDEN; ++j)
        acc = fmaf(fmaxf(h[j], 0.0f), w2[j], acc);

    out[i] = 1.0f / (1.0f + __expf(-acc));
}

// ---------------- fallback: proven v1 fp32 kernel ----------------
__global__ __launch_bounds__(256) void tiny_dlrm_kernel(
    const int*   __restrict__ user_id,
    const int*   __restrict__ item_id,
    const int*   __restrict__ cat_id,
    const float* __restrict__ dense,
    const float* __restrict__ user_table,
    const float* __restrict__ item_table,
    const float* __restrict__ cat_table,
    const float* __restrict__ w1,
    const float* __restrict__ b1,
    const float* __restrict__ w2,
    const float* __restrict__ b2,
    float*       __restrict__ out,
    int batch)
{
    int i = blockIdx.x * blockDim.x + threadIdx.x;
    if (i >= batch) return;

    int u = user_id[i];
    int v = item_id[i];
    int c = cat_id[i];

    const float4* up = (const float4*)(user_table + (size_t)u * 8);
    const float4* ip = (const float4*)(item_table + (size_t)v * 8);
    const float4* cp = (const float4*)(cat_table  + (size_t)c * 8);
    float4 u0 = up[0], u1 = up[1];
    float4 i0 = ip[0], i1 = ip[1];
    float4 c0 = cp[0], c1 = cp[1];
    float2 dd = ((const float2*)dense)[i];

    float f[IN_DIM] = {
        u0.x, u0.y, u0.z, u0.w, u1.x, u1.y, u1.z, u1.w,
        i0.x, i0.y, i0.z, i0.w, i1.x, i1.y, i1.z, i1.w,
        c0.x, c0.y, c0.z, c0.w, c1.x, c1.y, c1.z, c1.w,
        dd.x, dd.y
    };

    float h[HIDDEN];
#pragma unroll
    for (int j = 0; j < HIDDEN; ++j) h[j] = b1[j];
#pragma unroll
    for (int k = 0; k < IN_DIM; ++k) {
        float fk = f[k];
#pragma unroll
        for (int j = 0; j < HIDDEN; ++j)
            h[j] = fmaf(fk, w1[k * HIDDEN + j], h[j]);
    }
    float acc = b2[0];
#pragma unroll
    for (int j = 0; j < HIDDEN; ++j)
        acc = fmaf(fmaxf(h[j], 0.0f), w2[j], acc);

    out[i] = 1.0f / (1.0f + __expf(-acc));
}

extern "C" void kernel_launch(void* const* d_in, const int* in_sizes, int n_in,
                              void* d_out, int out_size, void* d_ws, size_t ws_size,
                              hipStream_t stream) {
    const int*   user_id    = (const int*)d_in[0];
    const int*   item_id    = (const int*)d_in[1];
    const int*   cat_id     = (const int*)d_in[2];
    const float* dense      = (const float*)d_in[3];
    const float* user_table = (const float*)d_in[4];
    const float* item_table = (const float*)d_in[5];
    const float* cat_table  = (const float*)d_in[6];
    const float* w1         = (const float*)d_in[7];
    const float* b1         = (const float*)d_in[8];
    const float* w2         = (const float*)d_in[9];
    const float* b2         = (const float*)d_in[10];
    float* out = (float*)d_out;

    int batch = in_sizes[0];
    int user_rows = in_sizes[4] / 8;   // 1,000,000
    int item_rows = in_sizes[5] / 8;   // 1,000,000

    size_t user_bytes = (size_t)user_rows * 8 * sizeof(_Float16);
    size_t need = user_bytes + (size_t)item_rows * 8 * sizeof(_Float16);

    int block = 256;
    int grid = (batch + block - 1) / block;

    if (ws_size >= need && user_rows == item_rows) {
        _Float16* user_h = (_Float16*)d_ws;
        _Float16* item_h = (_Float16*)((char*)d_ws + user_bytes);

        int rp_threads = 2 * user_rows;
        int rp_grid = (rp_threads + block - 1) / block;
        repack_kernel<<<rp_grid, block, 0, stream>>>(
            user_table, item_table, user_h, item_h, user_rows);

        tiny_dlrm_h_kernel<<<grid, block, 0, stream>>>(
            user_id, item_id, cat_id, dense,
            user_h, item_h, cat_table,
            w1, b1, w2, b2, out, batch);
    } else {
        tiny_dlrm_kernel<<<grid, block, 0, stream>>>(
            user_id, item_id, cat_id, dense,
            user_table, item_table, cat_table,
            w1, b1, w2, b2, out, batch);
    }
}